// Round 4
// baseline (265.685 us; speedup 1.0000x reference)
//
#include <hip/hip_runtime.h>
#include <hip/hip_bf16.h>

static constexpr int Hh = 56, Wd = 56, HWsz = 3136;
static constexpr float EPS = 1e-5f;

// ---------------------------------------------------------------------------
// prep: transpose weights so inner loops read contiguous scalar runs.
// ---------------------------------------------------------------------------
__global__ __launch_bounds__(256) void prep_transpose(
    const float* __restrict__ w1, const float* __restrict__ w3,
    const float* __restrict__ c1w,
    float* __restrict__ w1t, float* __restrict__ w3t, float* __restrict__ c1wt)
{
    const int idx = blockIdx.x * 256 + threadIdx.x;   // grid 64 -> 16384
    {
        const int c = idx >> 6, o = idx & 63;
        w1t[idx] = w1[o * 256 + c];
    }
    {
        const int c = idx >> 8, o = idx & 255;
        w3t[idx] = w3[o * 64 + c];
    }
    if (idx < 1024) {
        const int c = idx >> 4, g = idx & 15;
        c1wt[idx] = c1w[g * 64 + c];
    }
}

// ---------------------------------------------------------------------------
// K1: conv1 (1x1, 256->64) + BN1 + ReLU -> out1; then t = relu(bn(c1w@out1))
// (16 values/pixel) -> tbuf. 512 thr; 64 px x 64 out; thread = 1 px x 8 outs.
// unroll 4 so scalar weight loads (32 SGPR/body) can be double-buffered.
// ---------------------------------------------------------------------------
__global__ __launch_bounds__(512) void k1_conv1_branch(
    const float* __restrict__ x,
    const float* __restrict__ w1t,
    const float* __restrict__ bn1g, const float* __restrict__ bn1b,
    const float* __restrict__ bn1m, const float* __restrict__ bn1v,
    const float* __restrict__ c1wt,
    const float* __restrict__ ibg, const float* __restrict__ ibb,
    const float* __restrict__ ibm, const float* __restrict__ ibv,
    float* __restrict__ out1, float* __restrict__ tbuf)
{
    __shared__ float lds[64 * 64];   // 16 KB: [channel][pixel]
    const int tid  = threadIdx.x;
    const int lane = tid & 63;
    const int wv   = __builtin_amdgcn_readfirstlane(tid >> 6);   // 0..7
    const int pix0 = blockIdx.x * 64;
    const int b    = pix0 / HWsz;
    const int hw0  = pix0 - b * HWsz;
    const float* xb = x + (size_t)b * 256 * HWsz + hw0;

    const int o0 = wv * 8;
    float acc[8];
#pragma unroll
    for (int i = 0; i < 8; ++i) acc[i] = 0.f;

    for (int c0 = 0; c0 < 256; c0 += 64) {
        __syncthreads();
#pragma unroll
        for (int i = 0; i < 8; ++i) {
            const int ch = wv * 8 + i;
            lds[ch * 64 + lane] = xb[(size_t)(c0 + ch) * HWsz + lane];
        }
        __syncthreads();
#pragma unroll 4
        for (int c = 0; c < 64; ++c) {
            const float xv = lds[c * 64 + lane];
            const float* wr = w1t + (c0 + c) * 64 + o0;   // contiguous 8 -> s_load
#pragma unroll
            for (int i = 0; i < 8; ++i)
                acc[i] = fmaf(wr[i], xv, acc[i]);
        }
    }

    // BN1 + ReLU; write out1 and restage tile
    __syncthreads();
    {
        float* o1p = out1 + (size_t)b * 64 * HWsz + hw0 + lane;
#pragma unroll
        for (int i = 0; i < 8; ++i) {
            const int o = o0 + i;
            const float s = bn1g[o] * rsqrtf(bn1v[o] + EPS);
            const float v = fmaxf(fmaf(acc[i], s, bn1b[o] - bn1m[o] * s), 0.f);
            lds[o * 64 + lane] = v;
            o1p[(size_t)o * HWsz] = v;
        }
    }
    __syncthreads();

    // t: wave wv computes g = 2*wv, 2*wv+1
    const int g0 = wv * 2;
    float ta0 = 0.f, ta1 = 0.f;
#pragma unroll 8
    for (int c = 0; c < 64; ++c) {
        const float v = lds[c * 64 + lane];
        ta0 = fmaf(c1wt[c * 16 + g0], v, ta0);
        ta1 = fmaf(c1wt[c * 16 + g0 + 1], v, ta1);
    }
    {
        const float s0 = ibg[g0] * rsqrtf(ibv[g0] + EPS);
        const float s1 = ibg[g0 + 1] * rsqrtf(ibv[g0 + 1] + EPS);
        float* tp = tbuf + ((size_t)b * 16 + g0) * HWsz + hw0 + lane;
        tp[0]    = fmaxf(fmaf(ta0, s0, ibb[g0] - ibm[g0] * s0), 0.f);
        tp[HWsz] = fmaxf(fmaf(ta1, s1, ibb[g0 + 1] - ibm[g0 + 1] * s1), 0.f);
    }
}

// ---------------------------------------------------------------------------
// K2: involution (K=7, pad=3) + BN2 + ReLU, weights generated inline from t.
// grid (4 row-tiles, 64 b*g), block 448 (16 rows x 28 cols, 2 px/thread).
// Two 8-channel LDS passes; per-kh weight materialization from t (14 live
// regs); c2w g-slice + bias staged in LDS (uniform broadcast reads).
// ---------------------------------------------------------------------------
__global__ __launch_bounds__(448) void k2_involution(
    const float* __restrict__ out1, const float* __restrict__ tbuf,
    const float* __restrict__ c2w, const float* __restrict__ c2b,
    const float* __restrict__ bn2g, const float* __restrict__ bn2b,
    const float* __restrict__ bn2m, const float* __restrict__ bn2v,
    float* __restrict__ out2)
{
    __shared__ float lds[8 * 22 * 64];   // 44 KB halo tile
    __shared__ float wq[49 * 16];        // c2w slice for this g
    __shared__ float wb[49];             // c2b slice
    const int r0  = blockIdx.x * 16;
    const int b   = blockIdx.y >> 2, g = blockIdx.y & 3;

    const int tid = threadIdx.x;
    const int row = tid / 28;
    const int txw = tid - row * 28;
    const int cb  = 2 * txw;
    const bool ok = (r0 + row) < Hh;
    const int hw  = (r0 + row) * Wd + cb;

    for (int i = tid; i < 49 * 16; i += 448) wq[i] = c2w[g * 49 * 16 + i];
    if (tid < 49) wb[tid] = c2b[g * 49 + tid];

    float2 tv[16];
    if (ok) {
        const float* tp = tbuf + (size_t)b * 16 * HWsz + hw;
#pragma unroll
        for (int q = 0; q < 16; ++q)
            tv[q] = *(const float2*)(tp + (size_t)q * HWsz);
    }

    float2 acc[16];
#pragma unroll
    for (int i = 0; i < 16; ++i) { acc[i].x = 0.f; acc[i].y = 0.f; }

    for (int pass = 0; pass < 2; ++pass) {
        const int ch0 = g * 16 + pass * 8;
        __syncthreads();
        const float* src = out1 + ((size_t)b * 64 + ch0) * HWsz;
#pragma unroll
        for (int c = 0; c < 8; ++c) {
            for (int idx = tid; idx < 22 * 64; idx += 448) {
                const int rr = idx >> 6, cc = idx & 63;
                const int gr = r0 + rr - 3, gc = cc - 3;
                float v = 0.f;
                if (cc < 62 && gr >= 0 && gr < Hh && gc >= 0 && gc < Wd)
                    v = src[(size_t)c * HWsz + gr * Wd + gc];
                lds[(c * 22 + rr) * 64 + cc] = v;
            }
        }
        __syncthreads();

        if (ok) {
#pragma unroll
            for (int kh = 0; kh < 7; ++kh) {
                // materialize this kh-row's 7 per-pixel weights from t
                float2 wk[7];
#pragma unroll
                for (int kw = 0; kw < 7; ++kw) {
                    const int j = kh * 7 + kw;
                    const float* cw = &wq[j * 16];
                    float ax = wb[j], ay = ax;
#pragma unroll
                    for (int q = 0; q < 16; ++q) {
                        ax = fmaf(cw[q], tv[q].x, ax);
                        ay = fmaf(cw[q], tv[q].y, ay);
                    }
                    wk[kw].x = ax; wk[kw].y = ay;
                }
#pragma unroll
                for (int c8 = 0; c8 < 8; ++c8) {
                    const float* lrow = &lds[(c8 * 22 + row + kh) * 64 + cb];
                    float win[8];
                    *(float2*)&win[0] = *(const float2*)(lrow + 0);
                    *(float2*)&win[2] = *(const float2*)(lrow + 2);
                    *(float2*)&win[4] = *(const float2*)(lrow + 4);
                    *(float2*)&win[6] = *(const float2*)(lrow + 6);
                    const int ci = pass * 8 + c8;
#pragma unroll
                    for (int kw = 0; kw < 7; ++kw) {
                        acc[ci].x = fmaf(wk[kw].x, win[kw], acc[ci].x);
                        acc[ci].y = fmaf(wk[kw].y, win[kw + 1], acc[ci].y);
                    }
                }
            }
        }
    }

    if (ok) {
        float* op = out2 + ((size_t)b * 64 + g * 16) * HWsz + hw;
#pragma unroll
        for (int i = 0; i < 16; ++i) {
            const int ch = g * 16 + i;
            const float s   = bn2g[ch] * rsqrtf(bn2v[ch] + EPS);
            const float off = bn2b[ch] - bn2m[ch] * s;
            float2 v;
            v.x = fmaxf(fmaf(acc[i].x, s, off), 0.f);
            v.y = fmaxf(fmaf(acc[i].y, s, off), 0.f);
            *(float2*)(op + (size_t)i * HWsz) = v;
        }
    }
}

// ---------------------------------------------------------------------------
// K3: conv3 (1x1, 64->256) + BN3 + residual + ReLU
// grid (784,2), 512 thr: 64 px x 128 outs; thread = 1 px x 16 outs.
// unroll 2 (32 SGPR weight footprint/body -> scalar-load prefetch slack).
// ---------------------------------------------------------------------------
__global__ __launch_bounds__(512) void k3_conv3(
    const float* __restrict__ out2, const float* __restrict__ x,
    const float* __restrict__ w3t,
    const float* __restrict__ bn3g, const float* __restrict__ bn3b,
    const float* __restrict__ bn3m, const float* __restrict__ bn3v,
    float* __restrict__ out)
{
    __shared__ float lds[64 * 64];   // 16 KB
    const int tid  = threadIdx.x;
    const int lane = tid & 63;
    const int wv   = __builtin_amdgcn_readfirstlane(tid >> 6);   // 0..7
    const int pix0 = blockIdx.x * 64;
    const int b    = pix0 / HWsz;
    const int hw0  = pix0 - b * HWsz;

    const float* ip = out2 + (size_t)b * 64 * HWsz + hw0 + lane;
#pragma unroll
    for (int i = 0; i < 8; ++i) {
        const int ch = wv * 8 + i;
        lds[ch * 64 + lane] = ip[(size_t)ch * HWsz];
    }
    __syncthreads();

    const int o0 = blockIdx.y * 128 + wv * 16;
    float acc[16];
#pragma unroll
    for (int i = 0; i < 16; ++i) acc[i] = 0.f;

#pragma unroll 2
    for (int c = 0; c < 64; ++c) {
        const float v = lds[c * 64 + lane];
        const float* wr = w3t + c * 256 + o0;    // contiguous 16 -> s_load
#pragma unroll
        for (int i = 0; i < 16; ++i)
            acc[i] = fmaf(wr[i], v, acc[i]);
    }

    const float* xp = x   + ((size_t)b * 256 + o0) * HWsz + hw0 + lane;
    float*       op = out + ((size_t)b * 256 + o0) * HWsz + hw0 + lane;
#pragma unroll 4
    for (int i = 0; i < 16; ++i) {
        const int o = o0 + i;
        const float s   = bn3g[o] * rsqrtf(bn3v[o] + EPS);
        const float off = bn3b[o] - bn3m[o] * s;
        const float val = fmaf(acc[i], s, off) + xp[(size_t)i * HWsz];
        op[(size_t)i * HWsz] = fmaxf(val, 0.f);
    }
}

extern "C" void kernel_launch(void* const* d_in, const int* in_sizes, int n_in,
                              void* d_out, int out_size, void* d_ws, size_t ws_size,
                              hipStream_t stream)
{
    const float* x    = (const float*)d_in[0];
    const float* w1   = (const float*)d_in[1];
    const float* bn1g = (const float*)d_in[2];
    const float* bn1b = (const float*)d_in[3];
    const float* bn1m = (const float*)d_in[4];
    const float* bn1v = (const float*)d_in[5];
    const float* c1w  = (const float*)d_in[6];
    const float* ibg  = (const float*)d_in[7];
    const float* ibb  = (const float*)d_in[8];
    const float* ibm  = (const float*)d_in[9];
    const float* ibv  = (const float*)d_in[10];
    const float* c2w  = (const float*)d_in[11];
    const float* c2b  = (const float*)d_in[12];
    const float* bn2g = (const float*)d_in[13];
    const float* bn2b = (const float*)d_in[14];
    const float* bn2m = (const float*)d_in[15];
    const float* bn2v = (const float*)d_in[16];
    const float* w3   = (const float*)d_in[17];
    const float* bn3g = (const float*)d_in[18];
    const float* bn3b = (const float*)d_in[19];
    const float* bn3m = (const float*)d_in[20];
    const float* bn3v = (const float*)d_in[21];

    // ws (floats): out1 [0, 3211264) | out2 [3211264, 6422528)
    //              w1t 16384 | w3t 16384 | c1wt 1024
    float* out1 = (float*)d_ws;
    float* out2 = (float*)d_ws + 3211264;
    float* w1t  = (float*)d_ws + 6422528;
    float* w3t  = w1t + 16384;
    float* c1wt = w3t + 16384;
    // t [16,16,3136] fp32 (3.2 MB) lives in d_out — dead before k3 writes out
    float* tbuf = (float*)d_out;

    prep_transpose<<<dim3(64), dim3(256), 0, stream>>>(w1, w3, c1w, w1t, w3t, c1wt);

    k1_conv1_branch<<<dim3(784), dim3(512), 0, stream>>>(
        x, w1t, bn1g, bn1b, bn1m, bn1v, c1wt, ibg, ibb, ibm, ibv,
        out1, tbuf);

    k2_involution<<<dim3(4, 64), dim3(448), 0, stream>>>(
        out1, tbuf, c2w, c2b, bn2g, bn2b, bn2m, bn2v, out2);

    k3_conv3<<<dim3(784, 2), dim3(512), 0, stream>>>(
        out2, x, w3t, bn3g, bn3b, bn3m, bn3v, (float*)d_out);
}

// Round 5
// 248.191 us; speedup vs baseline: 1.0705x; 1.0705x over previous
//
#include <hip/hip_runtime.h>
#include <hip/hip_bf16.h>

static constexpr int Hh = 56, Wd = 56, HWsz = 3136;
static constexpr float EPS = 1e-5f;

// ---------------------------------------------------------------------------
// prep: transpose weights so inner loops read contiguous scalar runs.
// ---------------------------------------------------------------------------
__global__ __launch_bounds__(256) void prep_transpose(
    const float* __restrict__ w1, const float* __restrict__ w3,
    const float* __restrict__ c1w,
    float* __restrict__ w1t, float* __restrict__ w3t, float* __restrict__ c1wt)
{
    const int idx = blockIdx.x * 256 + threadIdx.x;   // grid 64 -> 16384
    {
        const int c = idx >> 6, o = idx & 63;
        w1t[idx] = w1[o * 256 + c];
    }
    {
        const int c = idx >> 8, o = idx & 255;
        w3t[idx] = w3[o * 64 + c];
    }
    if (idx < 1024) {
        const int c = idx >> 4, g = idx & 15;
        c1wt[idx] = c1w[g * 64 + c];
    }
}

// ---------------------------------------------------------------------------
// K1: conv1 (1x1, 256->64) + BN1 + ReLU -> out1; t = relu(bn(c1w@out1)) -> tbuf
// 512 thr; 64 px x 64 out; thread = 1 px x 8 outs.
// Double-buffered LDS staging: chunk k+1 global loads issue right after the
// barrier and overlap the 64-iteration FMA block on chunk k.
// ---------------------------------------------------------------------------
__global__ __launch_bounds__(512) void k1_conv1_branch(
    const float* __restrict__ x,
    const float* __restrict__ w1t,
    const float* __restrict__ bn1g, const float* __restrict__ bn1b,
    const float* __restrict__ bn1m, const float* __restrict__ bn1v,
    const float* __restrict__ c1wt,
    const float* __restrict__ ibg, const float* __restrict__ ibb,
    const float* __restrict__ ibm, const float* __restrict__ ibv,
    float* __restrict__ out1, float* __restrict__ tbuf)
{
    __shared__ float lds[2][64 * 64];   // 32 KB double buffer
    __shared__ float tls[16 * 64];      // t staging (reuses nothing)
    const int tid  = threadIdx.x;
    const int lane = tid & 63;
    const int wv   = __builtin_amdgcn_readfirstlane(tid >> 6);   // 0..7
    const int pix0 = blockIdx.x * 64;
    const int b    = pix0 / HWsz;
    const int hw0  = pix0 - b * HWsz;
    const float* xb = x + (size_t)b * 256 * HWsz + hw0 + lane;

    const int o0 = wv * 8;
    float acc[8];
#pragma unroll
    for (int i = 0; i < 8; ++i) acc[i] = 0.f;

    // prologue: stage chunk 0
    float r[8];
#pragma unroll
    for (int i = 0; i < 8; ++i)
        r[i] = xb[(size_t)(wv * 8 + i) * HWsz];
#pragma unroll
    for (int i = 0; i < 8; ++i)
        lds[0][(wv * 8 + i) * 64 + lane] = r[i];

    for (int k = 0; k < 4; ++k) {
        __syncthreads();
        if (k < 3) {
#pragma unroll
            for (int i = 0; i < 8; ++i)
                r[i] = xb[(size_t)((k + 1) * 64 + wv * 8 + i) * HWsz];
        }
        const float* cur = lds[k & 1];
#pragma unroll 4
        for (int c = 0; c < 64; ++c) {
            const float xv = cur[c * 64 + lane];
            const float* wr = w1t + (k * 64 + c) * 64 + o0;   // contiguous 8 -> s_load
#pragma unroll
            for (int i = 0; i < 8; ++i)
                acc[i] = fmaf(wr[i], xv, acc[i]);
        }
        if (k < 3) {
            float* nb = lds[(k + 1) & 1];
#pragma unroll
            for (int i = 0; i < 8; ++i)
                nb[(wv * 8 + i) * 64 + lane] = r[i];
        }
    }
    __syncthreads();

    // BN1 + ReLU; write out1 and restage tile into lds[0]
    {
        float* o1p = out1 + (size_t)b * 64 * HWsz + hw0 + lane;
#pragma unroll
        for (int i = 0; i < 8; ++i) {
            const int o = o0 + i;
            const float s = bn1g[o] * rsqrtf(bn1v[o] + EPS);
            const float v = fmaxf(fmaf(acc[i], s, bn1b[o] - bn1m[o] * s), 0.f);
            lds[0][o * 64 + lane] = v;
            o1p[(size_t)o * HWsz] = v;
        }
    }
    __syncthreads();

    // t: wave wv computes g = 2*wv, 2*wv+1
    const int g0 = wv * 2;
    float ta0 = 0.f, ta1 = 0.f;
#pragma unroll 8
    for (int c = 0; c < 64; ++c) {
        const float v = lds[0][c * 64 + lane];
        ta0 = fmaf(c1wt[c * 16 + g0], v, ta0);
        ta1 = fmaf(c1wt[c * 16 + g0 + 1], v, ta1);
    }
    {
        const float s0 = ibg[g0] * rsqrtf(ibv[g0] + EPS);
        const float s1 = ibg[g0 + 1] * rsqrtf(ibv[g0 + 1] + EPS);
        float* tp = tbuf + ((size_t)b * 16 + g0) * HWsz + hw0 + lane;
        tp[0]    = fmaxf(fmaf(ta0, s0, ibb[g0] - ibm[g0] * s0), 0.f);
        tp[HWsz] = fmaxf(fmaf(ta1, s1, ibb[g0 + 1] - ibm[g0 + 1] * s1), 0.f);
    }
    (void)tls;
}

// ---------------------------------------------------------------------------
// K2: involution (K=7, pad=3) + BN2 + ReLU, weights generated inline from t.
// grid (7 row-tiles x 64 bg x 2 ch-halves), block 448 = 8 rows x 56 cols,
// ONE pixel per thread (both bank parities used -> no systematic conflicts).
// 8 channels staged in LDS (28 KB); per-kh weight materialization from t.
// ---------------------------------------------------------------------------
__global__ __launch_bounds__(448) void k2_involution(
    const float* __restrict__ out1, const float* __restrict__ tbuf,
    const float* __restrict__ c2w, const float* __restrict__ c2b,
    const float* __restrict__ bn2g, const float* __restrict__ bn2b,
    const float* __restrict__ bn2m, const float* __restrict__ bn2v,
    float* __restrict__ out2)
{
    __shared__ float lds[8 * 14 * 64];   // 28 KB: 8 ch x (8+6) rows x 64 stride
    __shared__ float wq[49 * 16];
    __shared__ float wb[49];
    const int r0   = blockIdx.x * 8;                 // 7 tiles x 8 rows = 56 exact
    const int b    = blockIdx.y >> 2, g = blockIdx.y & 3;
    const int ch0  = g * 16 + blockIdx.z * 8;

    const int tid = threadIdx.x;
    const int row = tid / 56;            // 0..7
    const int col = tid - row * 56;      // 0..55
    const int hw  = (r0 + row) * Wd + col;

    for (int i = tid; i < 49 * 16; i += 448) wq[i] = c2w[g * 49 * 16 + i];
    if (tid < 49) wb[tid] = c2b[g * 49 + tid];

    // stage halo: 8 channels x 14 rows x 62 cols (stride 64)
    const float* src = out1 + ((size_t)b * 64 + ch0) * HWsz;
#pragma unroll
    for (int c = 0; c < 8; ++c) {
        for (int idx = tid; idx < 14 * 64; idx += 448) {
            const int rr = idx >> 6, cc = idx & 63;
            const int gr = r0 + rr - 3, gc = cc - 3;
            float v = 0.f;
            if (cc < 62 && gr >= 0 && gr < Hh && gc >= 0 && gc < Wd)
                v = src[(size_t)c * HWsz + gr * Wd + gc];
            lds[(c * 14 + rr) * 64 + cc] = v;
        }
    }

    // per-pixel t (16 values)
    float tv[16];
    {
        const float* tp = tbuf + (size_t)b * 16 * HWsz + hw;
#pragma unroll
        for (int q = 0; q < 16; ++q)
            tv[q] = tp[(size_t)q * HWsz];
    }
    __syncthreads();

    float acc[8];
#pragma unroll
    for (int i = 0; i < 8; ++i) acc[i] = 0.f;

#pragma unroll
    for (int kh = 0; kh < 7; ++kh) {
        // materialize this kh-row's 7 per-pixel weights from t
        float wk[7];
#pragma unroll
        for (int kw = 0; kw < 7; ++kw) {
            const int j = kh * 7 + kw;
            const float* cw = &wq[j * 16];
            float a = wb[j];
#pragma unroll
            for (int q = 0; q < 16; ++q)
                a = fmaf(cw[q], tv[q], a);
            wk[kw] = a;
        }
#pragma unroll
        for (int c8 = 0; c8 < 8; ++c8) {
            const float* lrow = &lds[(c8 * 14 + row + kh) * 64 + col];
#pragma unroll
            for (int kw = 0; kw < 7; ++kw)
                acc[c8] = fmaf(wk[kw], lrow[kw], acc[c8]);
        }
    }

    float* op = out2 + ((size_t)b * 64 + ch0) * HWsz + hw;
#pragma unroll
    for (int i = 0; i < 8; ++i) {
        const int ch = ch0 + i;
        const float s   = bn2g[ch] * rsqrtf(bn2v[ch] + EPS);
        const float off = bn2b[ch] - bn2m[ch] * s;
        op[(size_t)i * HWsz] = fmaxf(fmaf(acc[i], s, off), 0.f);
    }
}

// ---------------------------------------------------------------------------
// K3: conv3 (1x1, 64->256) + BN3 + residual + ReLU
// grid (784,2), 512 thr: 64 px x 128 outs; thread = 1 px x 16 outs.
// Residual x prefetched right after the barrier -> overlaps the GEMM loop.
// ---------------------------------------------------------------------------
__global__ __launch_bounds__(512) void k3_conv3(
    const float* __restrict__ out2, const float* __restrict__ x,
    const float* __restrict__ w3t,
    const float* __restrict__ bn3g, const float* __restrict__ bn3b,
    const float* __restrict__ bn3m, const float* __restrict__ bn3v,
    float* __restrict__ out)
{
    __shared__ float lds[64 * 64];   // 16 KB
    const int tid  = threadIdx.x;
    const int lane = tid & 63;
    const int wv   = __builtin_amdgcn_readfirstlane(tid >> 6);   // 0..7
    const int pix0 = blockIdx.x * 64;
    const int b    = pix0 / HWsz;
    const int hw0  = pix0 - b * HWsz;

    const float* ip = out2 + (size_t)b * 64 * HWsz + hw0 + lane;
#pragma unroll
    for (int i = 0; i < 8; ++i) {
        const int ch = wv * 8 + i;
        lds[ch * 64 + lane] = ip[(size_t)ch * HWsz];
    }
    __syncthreads();

    const int o0 = blockIdx.y * 128 + wv * 16;

    // residual prefetch: 16 streaming loads in flight during the GEMM loop
    const float* xp = x + ((size_t)b * 256 + o0) * HWsz + hw0 + lane;
    float xr[16];
#pragma unroll
    for (int i = 0; i < 16; ++i) xr[i] = xp[(size_t)i * HWsz];

    float acc[16];
#pragma unroll
    for (int i = 0; i < 16; ++i) acc[i] = 0.f;

#pragma unroll 2
    for (int c = 0; c < 64; ++c) {
        const float v = lds[c * 64 + lane];
        const float* wr = w3t + c * 256 + o0;    // contiguous 16 -> s_load
#pragma unroll
        for (int i = 0; i < 16; ++i)
            acc[i] = fmaf(wr[i], v, acc[i]);
    }

    float* op = out + ((size_t)b * 256 + o0) * HWsz + hw0 + lane;
#pragma unroll 4
    for (int i = 0; i < 16; ++i) {
        const int o = o0 + i;
        const float s   = bn3g[o] * rsqrtf(bn3v[o] + EPS);
        const float off = bn3b[o] - bn3m[o] * s;
        const float val = fmaf(acc[i], s, off) + xr[i];
        op[(size_t)i * HWsz] = fmaxf(val, 0.f);
    }
}

extern "C" void kernel_launch(void* const* d_in, const int* in_sizes, int n_in,
                              void* d_out, int out_size, void* d_ws, size_t ws_size,
                              hipStream_t stream)
{
    const float* x    = (const float*)d_in[0];
    const float* w1   = (const float*)d_in[1];
    const float* bn1g = (const float*)d_in[2];
    const float* bn1b = (const float*)d_in[3];
    const float* bn1m = (const float*)d_in[4];
    const float* bn1v = (const float*)d_in[5];
    const float* c1w  = (const float*)d_in[6];
    const float* ibg  = (const float*)d_in[7];
    const float* ibb  = (const float*)d_in[8];
    const float* ibm  = (const float*)d_in[9];
    const float* ibv  = (const float*)d_in[10];
    const float* c2w  = (const float*)d_in[11];
    const float* c2b  = (const float*)d_in[12];
    const float* bn2g = (const float*)d_in[13];
    const float* bn2b = (const float*)d_in[14];
    const float* bn2m = (const float*)d_in[15];
    const float* bn2v = (const float*)d_in[16];
    const float* w3   = (const float*)d_in[17];
    const float* bn3g = (const float*)d_in[18];
    const float* bn3b = (const float*)d_in[19];
    const float* bn3m = (const float*)d_in[20];
    const float* bn3v = (const float*)d_in[21];

    // ws (floats): out1 [0, 3211264) | out2 [3211264, 6422528)
    //              w1t 16384 | w3t 16384 | c1wt 1024
    float* out1 = (float*)d_ws;
    float* out2 = (float*)d_ws + 3211264;
    float* w1t  = (float*)d_ws + 6422528;
    float* w3t  = w1t + 16384;
    float* c1wt = w3t + 16384;
    // t [16,16,3136] fp32 (3.2 MB) lives in d_out — dead before k3 writes out
    float* tbuf = (float*)d_out;

    prep_transpose<<<dim3(64), dim3(256), 0, stream>>>(w1, w3, c1w, w1t, w3t, c1wt);

    k1_conv1_branch<<<dim3(784), dim3(512), 0, stream>>>(
        x, w1t, bn1g, bn1b, bn1m, bn1v, c1wt, ibg, ibb, ibm, ibv,
        out1, tbuf);

    k2_involution<<<dim3(7, 64, 2), dim3(448), 0, stream>>>(
        out1, tbuf, c2w, c2b, bn2g, bn2b, bn2m, bn2v, out2);

    k3_conv3<<<dim3(784, 2), dim3(512), 0, stream>>>(
        out2, x, w3t, bn3g, bn3b, bn3m, bn3v, (float*)d_out);
}